// Round 12
// baseline (27.344 us; speedup 1.0000x reference)
//
#include <hip/hip_runtime.h>
#include <stdint.h>

// Contrastive loss: B=16384, C=1000, D=128, fp32 in, scalar fp32 out.
// dist = f2 + c2 - 2*cross; loss = sum(relu(1-dist) over j!=target)/B.
//
// Round 12: r11 (24.3us best) + halved B-L2 traffic. Wave = 32 rows x 128
// cols (2 row-groups) -> total B-fragment reads 256->128 MB (L2 was at
// 60-75% of its 34.5 TB/s ceiling), each B frag feeds 2 MFMA chains.
// XCD row-ownership swizzle kept (r9): xcd = bid&7 owns rows
// [xcd*2048,(xcd+1)*2048) so feat enters each XCD L2 once (r8's null was
// missing this). ILP plumbing kept (r11): B depth-2 prefetch before the A
// prologue, dual independent MFMA chains (one per row-group), c2 hoisted.
// Lessons kept: no same-addr atomics (r2/r7), B converted once (r6),
// 3 plain nodes + tiny reduce (r10's DIY grid-sync regressed).
#define B_N 16384
#define C_N 1000
#define D_N 128
#define MARGIN 1.0f
#define NBLK 1024

typedef __attribute__((ext_vector_type(8))) short short8;  // 8 bf16
typedef __attribute__((ext_vector_type(4))) float f32x4;   // MFMA acc

__device__ __forceinline__ short f2bf(float f) {
    union { float f; uint32_t u; } v; v.f = f;
    uint32_t u = v.u;
    return (short)((u + 0x7FFFu + ((u >> 16) & 1u)) >> 16);
}

__device__ __forceinline__ short8 cvt8(const float4& v0, const float4& v1) {
    short8 s;
    s[0] = f2bf(v0.x); s[1] = f2bf(v0.y); s[2] = f2bf(v0.z); s[3] = f2bf(v0.w);
    s[4] = f2bf(v1.x); s[5] = f2bf(v1.y); s[6] = f2bf(v1.z); s[7] = f2bf(v1.w);
    return s;
}

__device__ __forceinline__ void load_bfrag(const short* __restrict__ bpre,
                                           int nb, int lane, short8* dst) {
    const short8* bp = reinterpret_cast<const short8*>(bpre + (size_t)nb * 2048) + lane;
    dst[0] = bp[0];
    dst[1] = bp[64];
    dst[2] = bp[128];
    dst[3] = bp[192];
}

// ---- kernel 1: cls -> bf16 fragment order + c2 (1e30 sentinel past C_N).
// Fragment (nb,kk): lane (l15,kg) holds cls[nb*16+l15][kk*32+kg*8 .. +8]
// at shorts nb*2048 + kk*512 + lane*8.
__global__ __launch_bounds__(64) void prep_kernel(
    const float* __restrict__ cls, short* __restrict__ bpre,
    float* __restrict__ c2p)
{
    const int nb   = blockIdx.x;       // 0..63
    const int lane = threadIdx.x;      // 0..63
    const int l15  = lane & 15;
    const int kg   = lane >> 4;
    const int col  = nb * 16 + l15;
    const bool valid = col < C_N;

    float sq = 0.f;
    #pragma unroll
    for (int kk = 0; kk < 4; ++kk) {
        float4 v0 = make_float4(0.f, 0.f, 0.f, 0.f);
        float4 v1 = make_float4(0.f, 0.f, 0.f, 0.f);
        if (valid) {
            const float* p = cls + (size_t)col * D_N + kk * 32 + kg * 8;
            v0 = *reinterpret_cast<const float4*>(p);
            v1 = *reinterpret_cast<const float4*>(p + 4);
        }
        sq += v0.x*v0.x + v0.y*v0.y + v0.z*v0.z + v0.w*v0.w
            + v1.x*v1.x + v1.y*v1.y + v1.z*v1.z + v1.w*v1.w;
        *reinterpret_cast<short8*>(bpre + (size_t)(nb * 2048 + kk * 512 + lane * 8))
            = cvt8(v0, v1);
    }
    sq += __shfl_xor(sq, 16);
    sq += __shfl_xor(sq, 32);
    if (lane < 16)
        c2p[nb * 16 + lane] = ((nb * 16 + lane) < C_N) ? sq : 1e30f;
}

// ---- kernel 2: block = 128 rows x 128 cols; wave = 32 rows (2 row-groups).
// Swizzle: xcd = bid&7, idx = bid>>3 (0..127), by = xcd*16 + (idx>>3),
// bx = idx&7 -- bijective, each XCD owns a disjoint 2048-row band of feat.
__global__ __launch_bounds__(256, 4) void closs_kernel(
    const float* __restrict__ feat, const long long* __restrict__ tgt,
    const short* __restrict__ bpre, const float* __restrict__ c2p,
    float* __restrict__ part)
{
    const int tid  = threadIdx.x;
    const int wave = tid >> 6;
    const int lane = tid & 63;
    const int l15  = lane & 15;
    const int kg   = lane >> 4;

    const int bid  = blockIdx.x;
    const int xcd  = bid & 7;
    const int idx  = bid >> 3;
    const int by   = (xcd << 4) | (idx >> 3);   // 0..127  row-tile (128 rows)
    const int bx   = idx & 7;                   // 0..7    col-slice (128 cols)
    const int row0 = by * 128 + wave * 32;      // wave's 32-row base
    const int nb0  = bx * 8;                    // 8 col-blocks per wave

    // ---- B prefetch (iter 0,1) FIRST: L2 latency hides under A's HBM ----
    short8 b0[4], b1[4];
    load_bfrag(bpre, nb0 + 0, lane, b0);
    load_bfrag(bpre, nb0 + 1, lane, b1);

    // ---- c2 for this lane's 8 columns, hoisted ----
    float c2r[8];
    #pragma unroll
    for (int i = 0; i < 8; ++i) c2r[i] = c2p[(nb0 + i) * 16 + l15];

    // ---- A: 2 row-groups x 16 rows x K=128 into registers + f2 ----
    short8 a[2][4];
    float  t[2][4];
    int    tg[2][4];
    #pragma unroll
    for (int rg = 0; rg < 2; ++rg) {
        const float* ap = feat + (size_t)(row0 + rg * 16 + l15) * D_N + kg * 8;
        float s = 0.f;
        #pragma unroll
        for (int kk = 0; kk < 4; ++kk) {
            float4 v0 = *reinterpret_cast<const float4*>(ap + kk * 32);
            float4 v1 = *reinterpret_cast<const float4*>(ap + kk * 32 + 4);
            s += v0.x*v0.x + v0.y*v0.y + v0.z*v0.z + v0.w*v0.w
               + v1.x*v1.x + v1.y*v1.y + v1.z*v1.z + v1.w*v1.w;
            a[rg][kk] = cvt8(v0, v1);
        }
        s += __shfl_xor(s, 16);
        s += __shfl_xor(s, 32);
        #pragma unroll
        for (int r = 0; r < 4; ++r) {
            t[rg][r]  = MARGIN - __shfl(s, kg * 4 + r);
            tg[rg][r] = (int)tgt[row0 + rg * 16 + kg * 4 + r];  // int64 input
        }
    }

    // ---- main loop: 8 col-blocks, depth-2 B rotation, 2 chains (rg0/rg1) ----
    float hsum = 0.f;
    #pragma unroll
    for (int i = 0; i < 8; ++i) {
        short8* bc = (i & 1) ? b1 : b0;   // static under full unroll
        f32x4 p0 = (f32x4){0.f, 0.f, 0.f, 0.f};
        f32x4 p1 = (f32x4){0.f, 0.f, 0.f, 0.f};
        p0 = __builtin_amdgcn_mfma_f32_16x16x32_bf16(a[0][0], bc[0], p0, 0, 0, 0);
        p1 = __builtin_amdgcn_mfma_f32_16x16x32_bf16(a[1][0], bc[0], p1, 0, 0, 0);
        p0 = __builtin_amdgcn_mfma_f32_16x16x32_bf16(a[0][1], bc[1], p0, 0, 0, 0);
        p1 = __builtin_amdgcn_mfma_f32_16x16x32_bf16(a[1][1], bc[1], p1, 0, 0, 0);
        p0 = __builtin_amdgcn_mfma_f32_16x16x32_bf16(a[0][2], bc[2], p0, 0, 0, 0);
        p1 = __builtin_amdgcn_mfma_f32_16x16x32_bf16(a[1][2], bc[2], p1, 0, 0, 0);
        p0 = __builtin_amdgcn_mfma_f32_16x16x32_bf16(a[0][3], bc[3], p0, 0, 0, 0);
        p1 = __builtin_amdgcn_mfma_f32_16x16x32_bf16(a[1][3], bc[3], p1, 0, 0, 0);
        if (i + 2 < 8)                     // refill consumed buffer (depth 2)
            load_bfrag(bpre, nb0 + i + 2, lane, bc);

        // Epilogue. C/D layout (m89): col = lane&15, row = kg*4 + r.
        // u = 2*acc + (MARGIN - f2 - c2); hinge active iff u > 0 (~never).
        const float c2v = c2r[i];
        float u0[4], u1[4];
        #pragma unroll
        for (int r = 0; r < 4; ++r) {
            u0[r] = __builtin_fmaf(2.0f, p0[r], t[0][r] - c2v);
            u1[r] = __builtin_fmaf(2.0f, p1[r], t[1][r] - c2v);
        }
        const float mx = fmaxf(fmaxf(fmaxf(u0[0], u0[1]), fmaxf(u0[2], u0[3])),
                               fmaxf(fmaxf(u1[0], u1[1]), fmaxf(u1[2], u1[3])));
        if (__any(mx > 0.0f)) {   // wave-uniform slow path: mask + accumulate
            const int col = (nb0 + i) * 16 + l15;
            #pragma unroll
            for (int r = 0; r < 4; ++r) {
                hsum += (col != tg[0][r]) ? fmaxf(0.0f, u0[r]) : 0.0f;
                hsum += (col != tg[1][r]) ? fmaxf(0.0f, u1[r]) : 0.0f;
            }
        }
    }

    // ---- reduce: wave -> block -> plain store (no contended atomics) ----
    #pragma unroll
    for (int off = 32; off; off >>= 1) hsum += __shfl_down(hsum, off);
    __shared__ float ws[4];
    if (lane == 0) ws[wave] = hsum;
    __syncthreads();
    if (tid == 0)
        part[bid] = ws[0] + ws[1] + ws[2] + ws[3];
}

// ---- kernel 3: reduce 1024 partials -> out[0] ----
__global__ __launch_bounds__(256) void reduce_kernel(
    const float* __restrict__ part, float* __restrict__ out)
{
    const int tid = threadIdx.x;
    float s = part[tid] + part[tid + 256] + part[tid + 512] + part[tid + 768];
    #pragma unroll
    for (int off = 32; off; off >>= 1) s += __shfl_down(s, off);
    __shared__ float ws[4];
    if ((tid & 63) == 0) ws[tid >> 6] = s;
    __syncthreads();
    if (tid == 0) out[0] = (ws[0] + ws[1] + ws[2] + ws[3]) * (1.0f / 16384.0f);
}

extern "C" void kernel_launch(void* const* d_in, const int* in_sizes, int n_in,
                              void* d_out, int out_size, void* d_ws, size_t ws_size,
                              hipStream_t stream) {
    const float*     feat = (const float*)d_in[0];
    const long long* tgt  = (const long long*)d_in[1];   // int64 targets
    const float*     cls  = (const float*)d_in[2];
    float*           out  = (float*)d_out;

    short* bpre = (short*)d_ws;                                      // 256 KiB
    float* c2p  = (float*)((char*)d_ws + 64 * 2048 * sizeof(short)); // 4 KiB
    float* part = c2p + 1024;                                        // 4 KiB

    prep_kernel<<<64, 64, 0, stream>>>(cls, bpre, c2p);
    closs_kernel<<<NBLK, 256, 0, stream>>>(feat, tgt, bpre, c2p, part);
    reduce_kernel<<<1, 256, 0, stream>>>(part, out);
}